// Round 1
// baseline (3217.327 us; speedup 1.0000x reference)
//
#include <hip/hip_runtime.h>

#define N_NODES 10000
#define N_EDGES 20000
#define DIM 64
#define NF 14
#define NB 200
#define NPG 50      // nodes per graph (batch = repeat(arange(200), 50))
#define STEPS 4
#define S2S_STEPS 3

typedef short short8 __attribute__((ext_vector_type(8)));
typedef float f32x4 __attribute__((ext_vector_type(4)));
typedef unsigned short u16;

__device__ __forceinline__ u16 f2bf(float f) {
  unsigned u = __float_as_uint(f);
  u += 0x7FFFu + ((u >> 16) & 1u);   // RNE
  return (u16)(u >> 16);
}
__device__ __forceinline__ float bf2f(u16 h) {
  return __uint_as_float(((unsigned)h) << 16);
}
__device__ __forceinline__ float lrelu(float v) { return v > 0.f ? v : 0.01f * v; }
__device__ __forceinline__ float sigm(float x) { return 1.f / (1.f + expf(-x)); }

// out = leaky_relu(x @ lin0_w + lin0_b)   [N,64]
__global__ __launch_bounds__(256) void k_lin0(const float* __restrict__ x,
    const float* __restrict__ w, const float* __restrict__ b,
    float* __restrict__ out) {
  int t = blockIdx.x * 256 + threadIdx.x;
  if (t >= N_NODES * DIM) return;
  int n = t >> 6, o = t & 63;
  float acc = b[o];
  #pragma unroll
  for (int f = 0; f < NF; ++f) acc += x[n * NF + f] * w[f * DIM + o];
  out[t] = lrelu(acc);
}

// h1 = leaky_relu(edge_attr @ enet_w1 + enet_b1)  -> bf16 [E,128]
__global__ __launch_bounds__(256) void k_h1(const float* __restrict__ ea,
    const float* __restrict__ w1, const float* __restrict__ b1,
    u16* __restrict__ h1) {
  int t = blockIdx.x * 256 + threadIdx.x;
  if (t >= N_EDGES * 128) return;
  int e = t >> 7, k = t & 127;
  float acc = b1[k];
  #pragma unroll
  for (int f = 0; f < 4; ++f) acc += ea[e * 4 + f] * w1[f * 128 + k];
  h1[t] = f2bf(lrelu(acc));
}

// Bt[c][k] = bf16(w2[k][(c&63)*64 + (c>>6)])  (column-permuted B, transposed)
// b2p[c]   = b2[(c&63)*64 + (c>>6)]
// crt[o][i]= conv_root[i][o]
__global__ __launch_bounds__(256) void k_prep(const float* __restrict__ w2,
    const float* __restrict__ b2, const float* __restrict__ cr,
    u16* __restrict__ Bt, float* __restrict__ b2p, float* __restrict__ crt) {
  int t = blockIdx.x * 256 + threadIdx.x;
  if (t < 4096 * 128) {
    int c = t >> 7, k = t & 127;
    Bt[t] = f2bf(w2[(size_t)k * 4096 + (c & 63) * 64 + (c >> 6)]);
  }
  if (t < 4096) {
    b2p[t] = b2[(t & 63) * 64 + (t >> 6)];
    crt[t] = cr[(t & 63) * 64 + (t >> 6)];
  }
}

__global__ __launch_bounds__(256) void k_cnt(const int* __restrict__ dst,
                                             float* __restrict__ cnt) {
  int t = blockIdx.x * 256 + threadIdx.x;
  if (t < N_EDGES) atomicAdd(cnt + dst[t], 1.f);
}

// We_t = h1 @ Bt^T + b2p   M=20000 N=4096 K=128, bf16 in, bf16 out, f32 accum
// 128x128 tile, 4 waves, K=128 in one shot (4 MFMA k-steps), LDS pad +8 bf16.
__global__ __launch_bounds__(256) void k_gemm(const u16* __restrict__ A,
    const u16* __restrict__ Bt, const float* __restrict__ bias,
    u16* __restrict__ C) {
  __shared__ __align__(16) u16 As[128 * 136];
  __shared__ __align__(16) u16 Bs[128 * 136];
  const int tid = threadIdx.x;
  const int m0 = blockIdx.x * 128;
  const int n0 = blockIdx.y * 128;
  #pragma unroll
  for (int it = 0; it < 8; ++it) {
    int chunk = tid + it * 256;          // 0..2047
    int row = chunk >> 4;                // 0..127
    int kc = (chunk & 15) * 8;           // 0..120
    int grow = m0 + row;
    short8 va = {0, 0, 0, 0, 0, 0, 0, 0};
    if (grow < N_EDGES) va = *(const short8*)(A + (size_t)grow * 128 + kc);
    *(short8*)(As + row * 136 + kc) = va;
    short8 vb = *(const short8*)(Bt + (size_t)(n0 + row) * 128 + kc);
    *(short8*)(Bs + row * 136 + kc) = vb;
  }
  __syncthreads();
  const int lane = tid & 63;
  const int wv = tid >> 6;     // wave -> column block wv*32
  const int lo = lane & 15;
  const int hi = lane >> 4;
  f32x4 acc[8][2];
  #pragma unroll
  for (int mf = 0; mf < 8; ++mf) {
    acc[mf][0] = (f32x4){0.f, 0.f, 0.f, 0.f};
    acc[mf][1] = (f32x4){0.f, 0.f, 0.f, 0.f};
  }
  #pragma unroll
  for (int kk = 0; kk < 4; ++kk) {
    const int kof = kk * 32 + hi * 8;
    short8 b0 = *(const short8*)(Bs + (wv * 32 + lo) * 136 + kof);
    short8 b1 = *(const short8*)(Bs + (wv * 32 + 16 + lo) * 136 + kof);
    #pragma unroll
    for (int mf = 0; mf < 8; ++mf) {
      short8 a = *(const short8*)(As + (mf * 16 + lo) * 136 + kof);
      acc[mf][0] = __builtin_amdgcn_mfma_f32_16x16x32_bf16(a, b0, acc[mf][0], 0, 0, 0);
      acc[mf][1] = __builtin_amdgcn_mfma_f32_16x16x32_bf16(a, b1, acc[mf][1], 0, 0, 0);
    }
  }
  #pragma unroll
  for (int mf = 0; mf < 8; ++mf) {
    int rbase = m0 + mf * 16 + hi * 4;   // C/D: row = 4*(lane>>4)+reg
    #pragma unroll
    for (int nf = 0; nf < 2; ++nf) {
      int col = n0 + wv * 32 + nf * 16 + lo;   // C/D: col = lane&15
      float bv = bias[col];
      #pragma unroll
      for (int r = 0; r < 4; ++r) {
        int gr = rbase + r;
        if (gr < N_EDGES) C[(size_t)gr * 4096 + col] = f2bf(acc[mf][nf][r] + bv);
      }
    }
  }
}

// msg[e,o] = sum_i out[src[e],i] * We_t[e][o*64+i];  atomic scatter-add to agg
__global__ __launch_bounds__(256) void k_msg(const u16* __restrict__ We,
    const float* __restrict__ out, const int* __restrict__ src,
    const int* __restrict__ dst, float* __restrict__ agg) {
  int e = blockIdx.x * 4 + (threadIdx.x >> 6);
  int o = threadIdx.x & 63;
  if (e >= N_EDGES) return;
  int s = __builtin_amdgcn_readfirstlane(src[e]);
  int d = __builtin_amdgcn_readfirstlane(dst[e]);
  const float* orow = out + (size_t)s * DIM;
  const u16* wp = We + (size_t)e * 4096 + o * 64;
  float acc = 0.f;
  #pragma unroll
  for (int j = 0; j < 8; ++j) {
    short8 wvv = *(const short8*)(wp + j * 8);
    #pragma unroll
    for (int t2 = 0; t2 < 8; ++t2) acc += bf2f((u16)wvv[t2]) * orow[j * 8 + t2];
  }
  atomicAdd(agg + (size_t)d * DIM + o, acc);
}

// m = lrelu(agg/denom + out@conv_root + bias); GRU(h=out): writes out_next
// 4 waves/block, 8 nodes/wave, lane = output dim.
__global__ __launch_bounds__(256) void k_node(const float* __restrict__ agg,
    const float* __restrict__ cnt, const float* __restrict__ out_cur,
    const float* __restrict__ crt, const float* __restrict__ cbias,
    const float* __restrict__ wih, const float* __restrict__ whh,
    const float* __restrict__ bih, const float* __restrict__ bhh,
    float* __restrict__ out_next) {
  __shared__ __align__(16) float lds_out[4][8][64];
  __shared__ __align__(16) float lds_m[4][8][64];
  const int w = threadIdx.x >> 6, o = threadIdx.x & 63;
  const int nbase = blockIdx.x * 32 + w * 8;
  #pragma unroll
  for (int nn = 0; nn < 8; ++nn) {
    int nd = nbase + nn;
    lds_out[w][nn][o] = (nd < N_NODES) ? out_cur[(size_t)nd * 64 + o] : 0.f;
  }
  __syncthreads();
  float acc[8];
  #pragma unroll
  for (int nn = 0; nn < 8; ++nn) {
    int nd = nbase + nn;
    acc[nn] = (nd < N_NODES)
        ? agg[(size_t)nd * 64 + o] / fmaxf(cnt[nd], 1.f) + cbias[o] : 0.f;
  }
  const float* crow = crt + o * 64;
  #pragma unroll
  for (int i4 = 0; i4 < 16; ++i4) {
    f32x4 wvv = *(const f32x4*)(crow + i4 * 4);
    #pragma unroll
    for (int nn = 0; nn < 8; ++nn) {
      f32x4 ov = *(const f32x4*)(&lds_out[w][nn][i4 * 4]);
      acc[nn] += ov[0] * wvv[0] + ov[1] * wvv[1] + ov[2] * wvv[2] + ov[3] * wvv[3];
    }
  }
  #pragma unroll
  for (int nn = 0; nn < 8; ++nn) lds_m[w][nn][o] = lrelu(acc[nn]);
  __syncthreads();
  float r_[8], z_[8], gic[8], ghc[8];
  #pragma unroll 1
  for (int p = 0; p < 3; ++p) {
    const int g = p * 64 + o;
    const float* wi = wih + g * 64;
    const float* wh = whh + g * 64;
    float bi = bih[g], bh = bhh[g];
    float ai[8], ah[8];
    #pragma unroll
    for (int nn = 0; nn < 8; ++nn) { ai[nn] = bi; ah[nn] = bh; }
    #pragma unroll
    for (int i4 = 0; i4 < 16; ++i4) {
      f32x4 wiv = *(const f32x4*)(wi + i4 * 4);
      f32x4 whv = *(const f32x4*)(wh + i4 * 4);
      #pragma unroll
      for (int nn = 0; nn < 8; ++nn) {
        f32x4 mv = *(const f32x4*)(&lds_m[w][nn][i4 * 4]);
        f32x4 hv = *(const f32x4*)(&lds_out[w][nn][i4 * 4]);
        ai[nn] += mv[0] * wiv[0] + mv[1] * wiv[1] + mv[2] * wiv[2] + mv[3] * wiv[3];
        ah[nn] += hv[0] * whv[0] + hv[1] * whv[1] + hv[2] * whv[2] + hv[3] * whv[3];
      }
    }
    if (p == 0) {
      #pragma unroll
      for (int nn = 0; nn < 8; ++nn) r_[nn] = sigm(ai[nn] + ah[nn]);
    } else if (p == 1) {
      #pragma unroll
      for (int nn = 0; nn < 8; ++nn) z_[nn] = sigm(ai[nn] + ah[nn]);
    } else {
      #pragma unroll
      for (int nn = 0; nn < 8; ++nn) { gic[nn] = ai[nn]; ghc[nn] = ah[nn]; }
    }
  }
  #pragma unroll
  for (int nn = 0; nn < 8; ++nn) {
    int nd = nbase + nn;
    if (nd < N_NODES) {
      float cand = tanhf(gic[nn] + r_[nn] * ghc[nn]);
      float hold = lds_out[w][nn][o];
      out_next[(size_t)nd * 64 + o] = (1.f - z_[nn]) * cand + z_[nn] * hold;
    }
  }
}

// Set2Set + final linear: one block per graph (50 contiguous nodes).
__global__ __launch_bounds__(256) void k_s2s(const float* __restrict__ out,
    const float* __restrict__ wih, const float* __restrict__ whh,
    const float* __restrict__ bih, const float* __restrict__ bhh,
    const float* __restrict__ l1w, const float* __restrict__ l1b,
    float* __restrict__ dout) {
  __shared__ float s_out[NPG * 64];
  __shared__ float s_q[128];
  __shared__ float s_hs[64];
  __shared__ float s_cs[64];
  __shared__ float s_g[256];
  __shared__ float s_e[64];
  __shared__ float s_a[64];
  const int gb = blockIdx.x, tid = threadIdx.x;
  for (int t = tid; t < NPG * 64; t += 256)
    s_out[t] = out[(size_t)gb * NPG * 64 + t];
  if (tid < 128) s_q[tid] = 0.f;
  if (tid < 64) { s_hs[tid] = 0.f; s_cs[tid] = 0.f; }
  __syncthreads();
  for (int it = 0; it < S2S_STEPS; ++it) {
    // LSTM gates: thread t = gate row t (i,f,g,o interleaved by 64)
    float acc = bih[tid] + bhh[tid];
    const float* wi = wih + tid * 128;
    #pragma unroll 8
    for (int j = 0; j < 128; ++j) acc += s_q[j] * wi[j];
    const float* wh = whh + tid * 64;
    #pragma unroll 8
    for (int j = 0; j < 64; ++j) acc += s_hs[j] * wh[j];
    s_g[tid] = acc;
    __syncthreads();
    if (tid < 64) {
      float i_ = s_g[tid], f_ = s_g[64 + tid], g_ = s_g[128 + tid], o_ = s_g[192 + tid];
      float cs = sigm(f_) * s_cs[tid] + sigm(i_) * tanhf(g_);
      s_cs[tid] = cs;
      s_hs[tid] = sigm(o_) * tanhf(cs);
    }
    __syncthreads();
    {
      int wvi = tid >> 6, ln = tid & 63;
      for (int node = wvi; node < NPG; node += 4) {
        float p = s_out[node * 64 + ln] * s_hs[ln];
        #pragma unroll
        for (int m = 32; m; m >>= 1) p += __shfl_xor(p, m, 64);
        if (ln == 0) s_e[node] = p;
      }
    }
    __syncthreads();
    if (tid < 64) {  // segment softmax over 50 nodes, wave 0
      float e = (tid < NPG) ? s_e[tid] : -1e30f;
      float mx = e;
      #pragma unroll
      for (int m = 32; m; m >>= 1) mx = fmaxf(mx, __shfl_xor(mx, m, 64));
      float a = (tid < NPG) ? expf(e - mx) : 0.f;
      float su = a;
      #pragma unroll
      for (int m = 32; m; m >>= 1) su += __shfl_xor(su, m, 64);
      s_a[tid] = a / su;
    }
    __syncthreads();
    if (tid < 64) {
      float r = 0.f;
      for (int n2 = 0; n2 < NPG; ++n2) r += s_a[n2] * s_out[n2 * 64 + tid];
      s_q[64 + tid] = r;
      s_q[tid] = s_hs[tid];
    }
    __syncthreads();
  }
  if (tid < 128) s_g[tid] = s_q[tid] * l1w[tid];
  __syncthreads();
  if (tid == 0) {
    float sm = 0.f;
    for (int j = 0; j < 128; ++j) sm += s_g[j];
    dout[gb] = sm + l1b[0];
  }
}

extern "C" void kernel_launch(void* const* d_in, const int* in_sizes, int n_in,
                              void* d_out, int out_size, void* d_ws, size_t ws_size,
                              hipStream_t stream) {
  (void)in_sizes; (void)n_in; (void)out_size; (void)ws_size;
  const float* x         = (const float*)d_in[0];
  const float* edge_attr = (const float*)d_in[1];
  const float* lin0_w    = (const float*)d_in[2];
  const float* lin0_b    = (const float*)d_in[3];
  const float* enet_w1   = (const float*)d_in[4];
  const float* enet_b1   = (const float*)d_in[5];
  const float* enet_w2   = (const float*)d_in[6];
  const float* enet_b2   = (const float*)d_in[7];
  const float* conv_root = (const float*)d_in[8];
  const float* conv_bias = (const float*)d_in[9];
  const float* gru_w_ih  = (const float*)d_in[10];
  const float* gru_w_hh  = (const float*)d_in[11];
  const float* gru_b_ih  = (const float*)d_in[12];
  const float* gru_b_hh  = (const float*)d_in[13];
  const float* s2s_w_ih  = (const float*)d_in[14];
  const float* s2s_w_hh  = (const float*)d_in[15];
  const float* s2s_b_ih  = (const float*)d_in[16];
  const float* s2s_b_hh  = (const float*)d_in[17];
  const float* lin1_w    = (const float*)d_in[18];
  const float* lin1_b    = (const float*)d_in[19];
  const int* edge_index  = (const int*)d_in[20];
  const int* srcp = edge_index;
  const int* dstp = edge_index + N_EDGES;

  char* ws = (char*)d_ws;
  size_t off = 0;
  auto carve = [&](size_t bytes) -> void* {
    void* p = ws + off;
    off += (bytes + 255) & ~(size_t)255;
    return p;
  };
  u16*   We    = (u16*)carve((size_t)N_EDGES * 4096 * 2);   // 163.84 MB
  u16*   h1    = (u16*)carve((size_t)N_EDGES * 128 * 2);    // 5.12 MB
  u16*   Bt    = (u16*)carve((size_t)4096 * 128 * 2);       // 1 MB
  float* b2p   = (float*)carve(4096 * 4);
  float* crt   = (float*)carve(4096 * 4);
  float* out_a = (float*)carve((size_t)N_NODES * 64 * 4);
  float* out_b = (float*)carve((size_t)N_NODES * 64 * 4);
  float* aggb  = (float*)carve((size_t)N_NODES * 64 * 4);
  float* cnt   = (float*)carve(N_NODES * 4);

  k_lin0<<<(N_NODES * DIM + 255) / 256, 256, 0, stream>>>(x, lin0_w, lin0_b, out_a);
  k_h1<<<(N_EDGES * 128 + 255) / 256, 256, 0, stream>>>(edge_attr, enet_w1, enet_b1, h1);
  k_prep<<<(4096 * 128 + 255) / 256, 256, 0, stream>>>(enet_w2, enet_b2, conv_root, Bt, b2p, crt);
  hipMemsetAsync(cnt, 0, N_NODES * 4, stream);
  k_cnt<<<(N_EDGES + 255) / 256, 256, 0, stream>>>(dstp, cnt);
  dim3 gg((N_EDGES + 127) / 128, 4096 / 128);
  k_gemm<<<gg, 256, 0, stream>>>(h1, Bt, b2p, We);

  float* cur = out_a;
  float* nxt = out_b;
  for (int s = 0; s < STEPS; ++s) {
    hipMemsetAsync(aggb, 0, (size_t)N_NODES * 64 * 4, stream);
    k_msg<<<(N_EDGES + 3) / 4, 256, 0, stream>>>(We, cur, srcp, dstp, aggb);
    k_node<<<(N_NODES + 31) / 32, 256, 0, stream>>>(aggb, cnt, cur, crt, conv_bias,
        gru_w_ih, gru_w_hh, gru_b_ih, gru_b_hh, nxt);
    float* t = cur; cur = nxt; nxt = t;
  }
  k_s2s<<<NB, 256, 0, stream>>>(cur, s2s_w_ih, s2s_w_hh, s2s_b_ih, s2s_b_hh,
      lin1_w, lin1_b, (float*)d_out);
}

// Round 2
// 905.850 us; speedup vs baseline: 3.5517x; 3.5517x over previous
//
#include <hip/hip_runtime.h>

#define N_NODES 10000
#define N_EDGES 20000
#define DIM 64
#define NF 14
#define NB 200
#define NPG 50      // nodes per graph (batch = repeat(arange(200), 50))
#define STEPS 4
#define S2S_STEPS 3

typedef short short8 __attribute__((ext_vector_type(8)));
typedef float f32x4 __attribute__((ext_vector_type(4)));
typedef unsigned short u16;

__device__ __forceinline__ u16 f2bf(float f) {
  unsigned u = __float_as_uint(f);
  u += 0x7FFFu + ((u >> 16) & 1u);   // RNE
  return (u16)(u >> 16);
}
__device__ __forceinline__ float bf2f(u16 h) {
  return __uint_as_float(((unsigned)h) << 16);
}
__device__ __forceinline__ float lrelu(float v) { return v > 0.f ? v : 0.01f * v; }
__device__ __forceinline__ float sigm(float x) { return 1.f / (1.f + expf(-x)); }

// out = leaky_relu(x @ lin0_w + lin0_b)   [N,64]
__global__ __launch_bounds__(256) void k_lin0(const float* __restrict__ x,
    const float* __restrict__ w, const float* __restrict__ b,
    float* __restrict__ out) {
  int t = blockIdx.x * 256 + threadIdx.x;
  if (t >= N_NODES * DIM) return;
  int n = t >> 6, o = t & 63;
  float acc = b[o];
  #pragma unroll
  for (int f = 0; f < NF; ++f) acc += x[n * NF + f] * w[f * DIM + o];
  out[t] = lrelu(acc);
}

// h1 = leaky_relu(edge_attr @ enet_w1 + enet_b1)  -> bf16 [E,128]
__global__ __launch_bounds__(256) void k_h1(const float* __restrict__ ea,
    const float* __restrict__ w1, const float* __restrict__ b1,
    u16* __restrict__ h1) {
  int t = blockIdx.x * 256 + threadIdx.x;
  if (t >= N_EDGES * 128) return;
  int e = t >> 7, k = t & 127;
  float acc = b1[k];
  #pragma unroll
  for (int f = 0; f < 4; ++f) acc += ea[e * 4 + f] * w1[f * 128 + k];
  h1[t] = f2bf(lrelu(acc));
}

// Bt[c][k] = bf16(w2[k][(c&63)*64 + (c>>6)])  (column-permuted B, transposed)
// b2p[c]   = b2[(c&63)*64 + (c>>6)]
// wihT[p*4096 + i*64 + o] = gru_w_ih[(p*64+o)*64 + i]   (coalesced gate weights)
// whhT likewise.
__global__ __launch_bounds__(256) void k_prep(const float* __restrict__ w2,
    const float* __restrict__ b2, const float* __restrict__ wih,
    const float* __restrict__ whh,
    u16* __restrict__ Bt, float* __restrict__ b2p,
    float* __restrict__ wihT, float* __restrict__ whhT) {
  int t = blockIdx.x * 256 + threadIdx.x;
  if (t < 4096 * 128) {
    int c = t >> 7, k = t & 127;
    Bt[t] = f2bf(w2[(size_t)k * 4096 + (c & 63) * 64 + (c >> 6)]);
  }
  if (t < 4096) {
    b2p[t] = b2[(t & 63) * 64 + (t >> 6)];
  }
  if (t < 3 * 64 * 64) {
    int p = t >> 12, rem = t & 4095, i = rem >> 6, o = rem & 63;
    int g = p * 64 + o;
    wihT[t] = wih[g * 64 + i];
    whhT[t] = whh[g * 64 + i];
  }
}

__global__ __launch_bounds__(256) void k_cnt(const int* __restrict__ dst,
                                             float* __restrict__ cnt) {
  int t = blockIdx.x * 256 + threadIdx.x;
  if (t < N_EDGES) atomicAdd(cnt + dst[t], 1.f);
}

// We_t = h1 @ Bt^T + b2p   M=20000 N=4096 K=128, bf16 in, bf16 out, f32 accum
// 128x128 tile, 4 waves, K=128 in one shot; C repacked via LDS -> 16B stores.
__global__ __launch_bounds__(256) void k_gemm(const u16* __restrict__ A,
    const u16* __restrict__ Bt, const float* __restrict__ bias,
    u16* __restrict__ C) {
  __shared__ __align__(16) u16 smem[2 * 128 * 136];
  u16* As = smem;
  u16* Bs = smem + 128 * 136;
  const int tid = threadIdx.x;
  const int m0 = blockIdx.x * 128;
  const int n0 = blockIdx.y * 128;
  #pragma unroll
  for (int it = 0; it < 8; ++it) {
    int chunk = tid + it * 256;          // 0..2047
    int row = chunk >> 4;                // 0..127
    int kc = (chunk & 15) * 8;           // 0..120
    int grow = m0 + row;
    short8 va = {0, 0, 0, 0, 0, 0, 0, 0};
    if (grow < N_EDGES) va = *(const short8*)(A + (size_t)grow * 128 + kc);
    *(short8*)(As + row * 136 + kc) = va;
    short8 vb = *(const short8*)(Bt + (size_t)(n0 + row) * 128 + kc);
    *(short8*)(Bs + row * 136 + kc) = vb;
  }
  __syncthreads();
  const int lane = tid & 63;
  const int wv = tid >> 6;     // wave -> column block wv*32
  const int lo = lane & 15;
  const int hi = lane >> 4;
  f32x4 acc[8][2];
  #pragma unroll
  for (int mf = 0; mf < 8; ++mf) {
    acc[mf][0] = (f32x4){0.f, 0.f, 0.f, 0.f};
    acc[mf][1] = (f32x4){0.f, 0.f, 0.f, 0.f};
  }
  #pragma unroll
  for (int kk = 0; kk < 4; ++kk) {
    const int kof = kk * 32 + hi * 8;
    short8 b0 = *(const short8*)(Bs + (wv * 32 + lo) * 136 + kof);
    short8 b1 = *(const short8*)(Bs + (wv * 32 + 16 + lo) * 136 + kof);
    #pragma unroll
    for (int mf = 0; mf < 8; ++mf) {
      short8 a = *(const short8*)(As + (mf * 16 + lo) * 136 + kof);
      acc[mf][0] = __builtin_amdgcn_mfma_f32_16x16x32_bf16(a, b0, acc[mf][0], 0, 0, 0);
      acc[mf][1] = __builtin_amdgcn_mfma_f32_16x16x32_bf16(a, b1, acc[mf][1], 0, 0, 0);
    }
  }
  __syncthreads();   // done reading As/Bs; reuse as C-tile
  u16* Cs = smem;    // 128*128 u16 = 32768 <= 34816 available
  #pragma unroll
  for (int nf = 0; nf < 2; ++nf) {
    int col = wv * 32 + nf * 16 + lo;    // C/D: col = lane&15
    float bv = bias[n0 + col];
    #pragma unroll
    for (int mf = 0; mf < 8; ++mf) {
      #pragma unroll
      for (int r = 0; r < 4; ++r) {
        int row = mf * 16 + hi * 4 + r;  // C/D: row = 4*(lane>>4)+reg
        Cs[row * 128 + col] = f2bf(acc[mf][nf][r] + bv);
      }
    }
  }
  __syncthreads();
  #pragma unroll
  for (int it = 0; it < 8; ++it) {
    int chunk = tid + it * 256;
    int row = chunk >> 4;
    int c8 = (chunk & 15) * 8;
    int grow = m0 + row;
    if (grow < N_EDGES)
      *(short8*)(C + (size_t)grow * 4096 + n0 + c8) = *(const short8*)(Cs + row * 128 + c8);
  }
}

// msg[e,o] = sum_i out[src[e],i] * We_t[e][o*64+i];  atomic scatter-add to agg
__global__ __launch_bounds__(256) void k_msg(const u16* __restrict__ We,
    const float* __restrict__ out, const int* __restrict__ src,
    const int* __restrict__ dst, float* __restrict__ agg) {
  int e = blockIdx.x * 4 + (threadIdx.x >> 6);
  int o = threadIdx.x & 63;
  if (e >= N_EDGES) return;
  int s = __builtin_amdgcn_readfirstlane(src[e]);
  int d = __builtin_amdgcn_readfirstlane(dst[e]);
  const float* orow = out + (size_t)s * DIM;
  const u16* wp = We + (size_t)e * 4096 + o * 64;
  float acc = 0.f;
  #pragma unroll
  for (int j = 0; j < 8; ++j) {
    short8 wvv = *(const short8*)(wp + j * 8);
    #pragma unroll
    for (int t2 = 0; t2 < 8; ++t2) acc += bf2f((u16)wvv[t2]) * orow[j * 8 + t2];
  }
  atomicAdd(agg + (size_t)d * DIM + o, acc);
}

// Node update: one node per wave, lane = output dim. No register arrays.
// m = lrelu(agg/denom + out@conv_root + cbias); GRU(h=out) -> out_next.
__global__ __launch_bounds__(256) void k_node(const float* __restrict__ agg,
    const float* __restrict__ cnt, const float* __restrict__ out_cur,
    const float* __restrict__ cr,        // conv_root [i][o], o contiguous
    const float* __restrict__ cbias,
    const float* __restrict__ wihT, const float* __restrict__ whhT,
    const float* __restrict__ bih, const float* __restrict__ bhh,
    float* __restrict__ out_next) {
  __shared__ float s_h[4][64];
  __shared__ float s_m[4][64];
  const int w = threadIdx.x >> 6, o = threadIdx.x & 63;
  const int nd = blockIdx.x * 4 + w;          // 2500 blocks * 4 = 10000 exact
  const float hval = out_cur[(size_t)nd * 64 + o];
  s_h[w][o] = hval;
  float acc = agg[(size_t)nd * 64 + o] / fmaxf(cnt[nd], 1.f) + cbias[o];
  __syncthreads();
  #pragma unroll 4
  for (int i = 0; i < 64; ++i) acc += s_h[w][i] * cr[i * 64 + o];
  s_m[w][o] = lrelu(acc);
  __syncthreads();
  float gi0 = bih[o],       gh0 = bhh[o];
  float gi1 = bih[64 + o],  gh1 = bhh[64 + o];
  float gi2 = bih[128 + o], gh2 = bhh[128 + o];
  #pragma unroll 4
  for (int i = 0; i < 64; ++i) {
    float mv = s_m[w][i], hv = s_h[w][i];
    int io = i * 64 + o;
    gi0 += mv * wihT[io];
    gh0 += hv * whhT[io];
    gi1 += mv * wihT[4096 + io];
    gh1 += hv * whhT[4096 + io];
    gi2 += mv * wihT[8192 + io];
    gh2 += hv * whhT[8192 + io];
  }
  float r_ = sigm(gi0 + gh0);
  float z_ = sigm(gi1 + gh1);
  float cand = tanhf(gi2 + r_ * gh2);
  out_next[(size_t)nd * 64 + o] = (1.f - z_) * cand + z_ * hval;
}

// Set2Set + final linear: one block per graph (50 contiguous nodes).
__global__ __launch_bounds__(256) void k_s2s(const float* __restrict__ out,
    const float* __restrict__ wih, const float* __restrict__ whh,
    const float* __restrict__ bih, const float* __restrict__ bhh,
    const float* __restrict__ l1w, const float* __restrict__ l1b,
    float* __restrict__ dout) {
  __shared__ float s_out[NPG * 64];
  __shared__ float s_q[128];
  __shared__ float s_hs[64];
  __shared__ float s_cs[64];
  __shared__ float s_g[256];
  __shared__ float s_e[64];
  __shared__ float s_a[64];
  const int gb = blockIdx.x, tid = threadIdx.x;
  for (int t = tid; t < NPG * 64; t += 256)
    s_out[t] = out[(size_t)gb * NPG * 64 + t];
  if (tid < 128) s_q[tid] = 0.f;
  if (tid < 64) { s_hs[tid] = 0.f; s_cs[tid] = 0.f; }
  __syncthreads();
  for (int it = 0; it < S2S_STEPS; ++it) {
    float acc = bih[tid] + bhh[tid];
    const float* wi = wih + tid * 128;
    #pragma unroll 8
    for (int j = 0; j < 128; ++j) acc += s_q[j] * wi[j];
    const float* wh = whh + tid * 64;
    #pragma unroll 8
    for (int j = 0; j < 64; ++j) acc += s_hs[j] * wh[j];
    s_g[tid] = acc;
    __syncthreads();
    if (tid < 64) {
      float i_ = s_g[tid], f_ = s_g[64 + tid], g_ = s_g[128 + tid], o_ = s_g[192 + tid];
      float cs = sigm(f_) * s_cs[tid] + sigm(i_) * tanhf(g_);
      s_cs[tid] = cs;
      s_hs[tid] = sigm(o_) * tanhf(cs);
    }
    __syncthreads();
    {
      int wvi = tid >> 6, ln = tid & 63;
      for (int node = wvi; node < NPG; node += 4) {
        float p = s_out[node * 64 + ln] * s_hs[ln];
        #pragma unroll
        for (int m = 32; m; m >>= 1) p += __shfl_xor(p, m, 64);
        if (ln == 0) s_e[node] = p;
      }
    }
    __syncthreads();
    if (tid < 64) {
      float e = (tid < NPG) ? s_e[tid] : -1e30f;
      float mx = e;
      #pragma unroll
      for (int m = 32; m; m >>= 1) mx = fmaxf(mx, __shfl_xor(mx, m, 64));
      float a = (tid < NPG) ? expf(e - mx) : 0.f;
      float su = a;
      #pragma unroll
      for (int m = 32; m; m >>= 1) su += __shfl_xor(su, m, 64);
      s_a[tid] = a / su;
    }
    __syncthreads();
    if (tid < 64) {
      float r = 0.f;
      for (int n2 = 0; n2 < NPG; ++n2) r += s_a[n2] * s_out[n2 * 64 + tid];
      s_q[64 + tid] = r;
      s_q[tid] = s_hs[tid];
    }
    __syncthreads();
  }
  if (tid < 128) s_g[tid] = s_q[tid] * l1w[tid];
  __syncthreads();
  if (tid == 0) {
    float sm = 0.f;
    for (int j = 0; j < 128; ++j) sm += s_g[j];
    dout[gb] = sm + l1b[0];
  }
}

extern "C" void kernel_launch(void* const* d_in, const int* in_sizes, int n_in,
                              void* d_out, int out_size, void* d_ws, size_t ws_size,
                              hipStream_t stream) {
  (void)in_sizes; (void)n_in; (void)out_size; (void)ws_size;
  const float* x         = (const float*)d_in[0];
  const float* edge_attr = (const float*)d_in[1];
  const float* lin0_w    = (const float*)d_in[2];
  const float* lin0_b    = (const float*)d_in[3];
  const float* enet_w1   = (const float*)d_in[4];
  const float* enet_b1   = (const float*)d_in[5];
  const float* enet_w2   = (const float*)d_in[6];
  const float* enet_b2   = (const float*)d_in[7];
  const float* conv_root = (const float*)d_in[8];
  const float* conv_bias = (const float*)d_in[9];
  const float* gru_w_ih  = (const float*)d_in[10];
  const float* gru_w_hh  = (const float*)d_in[11];
  const float* gru_b_ih  = (const float*)d_in[12];
  const float* gru_b_hh  = (const float*)d_in[13];
  const float* s2s_w_ih  = (const float*)d_in[14];
  const float* s2s_w_hh  = (const float*)d_in[15];
  const float* s2s_b_ih  = (const float*)d_in[16];
  const float* s2s_b_hh  = (const float*)d_in[17];
  const float* lin1_w    = (const float*)d_in[18];
  const float* lin1_b    = (const float*)d_in[19];
  const int* edge_index  = (const int*)d_in[20];
  const int* srcp = edge_index;
  const int* dstp = edge_index + N_EDGES;

  char* ws = (char*)d_ws;
  size_t off = 0;
  auto carve = [&](size_t bytes) -> void* {
    void* p = ws + off;
    off += (bytes + 255) & ~(size_t)255;
    return p;
  };
  u16*   We    = (u16*)carve((size_t)N_EDGES * 4096 * 2);   // 163.84 MB
  u16*   h1    = (u16*)carve((size_t)N_EDGES * 128 * 2);    // 5.12 MB
  u16*   Bt    = (u16*)carve((size_t)4096 * 128 * 2);       // 1 MB
  float* b2p   = (float*)carve(4096 * 4);
  float* wihT  = (float*)carve(3 * 64 * 64 * 4);
  float* whhT  = (float*)carve(3 * 64 * 64 * 4);
  float* out_a = (float*)carve((size_t)N_NODES * 64 * 4);
  float* out_b = (float*)carve((size_t)N_NODES * 64 * 4);
  float* aggb  = (float*)carve((size_t)N_NODES * 64 * 4);
  float* cnt   = (float*)carve(N_NODES * 4);

  k_lin0<<<(N_NODES * DIM + 255) / 256, 256, 0, stream>>>(x, lin0_w, lin0_b, out_a);
  k_h1<<<(N_EDGES * 128 + 255) / 256, 256, 0, stream>>>(edge_attr, enet_w1, enet_b1, h1);
  k_prep<<<(4096 * 128 + 255) / 256, 256, 0, stream>>>(enet_w2, enet_b2,
      gru_w_ih, gru_w_hh, Bt, b2p, wihT, whhT);
  hipMemsetAsync(cnt, 0, N_NODES * 4, stream);
  k_cnt<<<(N_EDGES + 255) / 256, 256, 0, stream>>>(dstp, cnt);
  dim3 gg((N_EDGES + 127) / 128, 4096 / 128);
  k_gemm<<<gg, 256, 0, stream>>>(h1, Bt, b2p, We);

  float* cur = out_a;
  float* nxt = out_b;
  for (int s = 0; s < STEPS; ++s) {
    hipMemsetAsync(aggb, 0, (size_t)N_NODES * 64 * 4, stream);
    k_msg<<<(N_EDGES + 3) / 4, 256, 0, stream>>>(We, cur, srcp, dstp, aggb);
    k_node<<<N_NODES / 4, 256, 0, stream>>>(aggb, cnt, cur, conv_root, conv_bias,
        wihT, whhT, gru_b_ih, gru_b_hh, nxt);
    float* t = cur; cur = nxt; nxt = t;
  }
  k_s2s<<<NB, 256, 0, stream>>>(cur, s2s_w_ih, s2s_w_hh, s2s_b_ih, s2s_b_hh,
      lin1_w, lin1_b, (float*)d_out);
}

// Round 3
// 388.873 us; speedup vs baseline: 8.2735x; 2.3294x over previous
//
#include <hip/hip_runtime.h>

#define N_NODES 10000
#define N_EDGES 20000
#define DIM 64
#define NF 14
#define NB 200
#define NPG 50      // nodes per graph (batch = repeat(arange(200), 50))
#define STEPS 4
#define S2S_STEPS 3

typedef short short8 __attribute__((ext_vector_type(8)));
typedef float f32x4 __attribute__((ext_vector_type(4)));
typedef unsigned short u16;

__device__ __forceinline__ u16 f2bf(float f) {
  unsigned u = __float_as_uint(f);
  u += 0x7FFFu + ((u >> 16) & 1u);   // RNE
  return (u16)(u >> 16);
}
__device__ __forceinline__ float bf2f(u16 h) {
  return __uint_as_float(((unsigned)h) << 16);
}
__device__ __forceinline__ float lrelu(float v) { return v > 0.f ? v : 0.01f * v; }
__device__ __forceinline__ float sigm(float x) { return 1.f / (1.f + expf(-x)); }

// out = leaky_relu(x @ lin0_w + lin0_b)   [N,64]
__global__ __launch_bounds__(256) void k_lin0(const float* __restrict__ x,
    const float* __restrict__ w, const float* __restrict__ b,
    float* __restrict__ out) {
  int t = blockIdx.x * 256 + threadIdx.x;
  if (t >= N_NODES * DIM) return;
  int n = t >> 6, o = t & 63;
  float acc = b[o];
  #pragma unroll
  for (int f = 0; f < NF; ++f) acc += x[n * NF + f] * w[f * DIM + o];
  out[t] = lrelu(acc);
}

// h1 = leaky_relu(edge_attr @ enet_w1 + enet_b1)  -> bf16 [E,128]
__global__ __launch_bounds__(256) void k_h1(const float* __restrict__ ea,
    const float* __restrict__ w1, const float* __restrict__ b1,
    u16* __restrict__ h1) {
  int t = blockIdx.x * 256 + threadIdx.x;
  if (t >= N_EDGES * 128) return;
  int e = t >> 7, k = t & 127;
  float acc = b1[k];
  #pragma unroll
  for (int f = 0; f < 4; ++f) acc += ea[e * 4 + f] * w1[f * 128 + k];
  h1[t] = f2bf(lrelu(acc));
}

// Streaming-friendly column permutation for We:
//   stored column c = i8*512 + o*8 + k  <->  weight element (i = i8*8+k, o)
// so k_msg's wave (lane=o) reads 1KB fully-contiguous chunks per i8.
// Bt[c][k'] = bf16(w2[k'][i(c)*64 + o(c)]);  b2p[c] = b2[i(c)*64 + o(c)]
// wihT[p*4096 + i*64 + o] = gru_w_ih[(p*64+o)*64 + i]; whhT likewise.
__global__ __launch_bounds__(256) void k_prep(const float* __restrict__ w2,
    const float* __restrict__ b2, const float* __restrict__ wih,
    const float* __restrict__ whh,
    u16* __restrict__ Bt, float* __restrict__ b2p,
    float* __restrict__ wihT, float* __restrict__ whhT) {
  int t = blockIdx.x * 256 + threadIdx.x;
  if (t < 4096 * 128) {
    int c = t >> 7, k = t & 127;
    int iw = (c >> 9) * 8 + (c & 7);
    int ow = (c >> 3) & 63;
    Bt[t] = f2bf(w2[(size_t)k * 4096 + iw * 64 + ow]);
  }
  if (t < 4096) {
    int iw = (t >> 9) * 8 + (t & 7);
    int ow = (t >> 3) & 63;
    b2p[t] = b2[iw * 64 + ow];
  }
  if (t < 3 * 64 * 64) {
    int p = t >> 12, rem = t & 4095, i = rem >> 6, o = rem & 63;
    int g = p * 64 + o;
    wihT[t] = wih[g * 64 + i];
    whhT[t] = whh[g * 64 + i];
  }
}

__global__ __launch_bounds__(256) void k_cnt(const int* __restrict__ dst,
                                             float* __restrict__ cnt) {
  int t = blockIdx.x * 256 + threadIdx.x;
  if (t < N_EDGES) atomicAdd(cnt + dst[t], 1.f);
}

// We = h1 @ Bt^T + b2p   M=20000 N=4096 K=128, bf16 in, bf16 out, f32 accum
// 128x128 tile, 4 waves, K=128 in one shot; C repacked via LDS -> 16B stores.
__global__ __launch_bounds__(256) void k_gemm(const u16* __restrict__ A,
    const u16* __restrict__ Bt, const float* __restrict__ bias,
    u16* __restrict__ C) {
  __shared__ __align__(16) u16 smem[2 * 128 * 136];
  u16* As = smem;
  u16* Bs = smem + 128 * 136;
  const int tid = threadIdx.x;
  const int m0 = blockIdx.x * 128;
  const int n0 = blockIdx.y * 128;
  #pragma unroll
  for (int it = 0; it < 8; ++it) {
    int chunk = tid + it * 256;          // 0..2047
    int row = chunk >> 4;                // 0..127
    int kc = (chunk & 15) * 8;           // 0..120
    int grow = m0 + row;
    short8 va = {0, 0, 0, 0, 0, 0, 0, 0};
    if (grow < N_EDGES) va = *(const short8*)(A + (size_t)grow * 128 + kc);
    *(short8*)(As + row * 136 + kc) = va;
    short8 vb = *(const short8*)(Bt + (size_t)(n0 + row) * 128 + kc);
    *(short8*)(Bs + row * 136 + kc) = vb;
  }
  __syncthreads();
  const int lane = tid & 63;
  const int wv = tid >> 6;     // wave -> column block wv*32
  const int lo = lane & 15;
  const int hi = lane >> 4;
  f32x4 acc[8][2];
  #pragma unroll
  for (int mf = 0; mf < 8; ++mf) {
    acc[mf][0] = (f32x4){0.f, 0.f, 0.f, 0.f};
    acc[mf][1] = (f32x4){0.f, 0.f, 0.f, 0.f};
  }
  #pragma unroll
  for (int kk = 0; kk < 4; ++kk) {
    const int kof = kk * 32 + hi * 8;
    short8 b0 = *(const short8*)(Bs + (wv * 32 + lo) * 136 + kof);
    short8 b1 = *(const short8*)(Bs + (wv * 32 + 16 + lo) * 136 + kof);
    #pragma unroll
    for (int mf = 0; mf < 8; ++mf) {
      short8 a = *(const short8*)(As + (mf * 16 + lo) * 136 + kof);
      acc[mf][0] = __builtin_amdgcn_mfma_f32_16x16x32_bf16(a, b0, acc[mf][0], 0, 0, 0);
      acc[mf][1] = __builtin_amdgcn_mfma_f32_16x16x32_bf16(a, b1, acc[mf][1], 0, 0, 0);
    }
  }
  __syncthreads();   // done reading As/Bs; reuse as C-tile
  u16* Cs = smem;    // 128*128 u16 = 32768 bytes x? (u16) fits in 2*128*136
  #pragma unroll
  for (int nf = 0; nf < 2; ++nf) {
    int col = wv * 32 + nf * 16 + lo;    // C/D: col = lane&15
    float bv = bias[n0 + col];
    #pragma unroll
    for (int mf = 0; mf < 8; ++mf) {
      #pragma unroll
      for (int r = 0; r < 4; ++r) {
        int row = mf * 16 + hi * 4 + r;  // C/D: row = 4*(lane>>4)+reg
        Cs[row * 128 + col] = f2bf(acc[mf][nf][r] + bv);
      }
    }
  }
  __syncthreads();
  #pragma unroll
  for (int it = 0; it < 8; ++it) {
    int chunk = tid + it * 256;
    int row = chunk >> 4;
    int c8 = (chunk & 15) * 8;
    int grow = m0 + row;
    if (grow < N_EDGES)
      *(short8*)(C + (size_t)grow * 4096 + n0 + c8) = *(const short8*)(Cs + row * 128 + c8);
  }
}

// msg[e,o] = sum_i out[src[e],i] * We_perm; perfectly coalesced We stream.
// Wave = edge, lane = o. Chunk i8: lane o loads 16B at e*8KB + i8*1KB + o*16B
// (wave covers 1KB contiguous), pairs with broadcast out[src][i8*8+k].
__global__ __launch_bounds__(256) void k_msg(const u16* __restrict__ We,
    const float* __restrict__ out, const int* __restrict__ src,
    const int* __restrict__ dst, float* __restrict__ agg) {
  __shared__ float s_o[4][64];
  const int w = threadIdx.x >> 6, o = threadIdx.x & 63;
  const int e = blockIdx.x * 4 + w;          // grid exact: 5000*4 = 20000
  const int s = __builtin_amdgcn_readfirstlane(src[e]);
  const int d = __builtin_amdgcn_readfirstlane(dst[e]);
  s_o[w][o] = out[(size_t)s * 64 + o];
  __syncthreads();
  const u16* wp = We + (size_t)e * 4096 + o * 8;
  float acc = 0.f;
  #pragma unroll
  for (int i8 = 0; i8 < 8; ++i8) {
    short8 wv = *(const short8*)(wp + i8 * 512);
    f32x4 o0 = *(const f32x4*)(&s_o[w][i8 * 8]);
    f32x4 o1 = *(const f32x4*)(&s_o[w][i8 * 8 + 4]);
    acc += bf2f((u16)wv[0]) * o0[0] + bf2f((u16)wv[1]) * o0[1]
         + bf2f((u16)wv[2]) * o0[2] + bf2f((u16)wv[3]) * o0[3]
         + bf2f((u16)wv[4]) * o1[0] + bf2f((u16)wv[5]) * o1[1]
         + bf2f((u16)wv[6]) * o1[2] + bf2f((u16)wv[7]) * o1[3];
  }
  atomicAdd(agg + (size_t)d * 64 + o, acc);
}

// Node update: one node per wave, lane = output dim. No register arrays.
// m = lrelu(agg/denom + out@conv_root + cbias); GRU(h=out) -> out_next.
__global__ __launch_bounds__(256) void k_node(const float* __restrict__ agg,
    const float* __restrict__ cnt, const float* __restrict__ out_cur,
    const float* __restrict__ cr,        // conv_root [i][o], o contiguous
    const float* __restrict__ cbias,
    const float* __restrict__ wihT, const float* __restrict__ whhT,
    const float* __restrict__ bih, const float* __restrict__ bhh,
    float* __restrict__ out_next) {
  __shared__ float s_h[4][64];
  __shared__ float s_m[4][64];
  const int w = threadIdx.x >> 6, o = threadIdx.x & 63;
  const int nd = blockIdx.x * 4 + w;          // 2500 blocks * 4 = 10000 exact
  const float hval = out_cur[(size_t)nd * 64 + o];
  s_h[w][o] = hval;
  float acc = agg[(size_t)nd * 64 + o] / fmaxf(cnt[nd], 1.f) + cbias[o];
  __syncthreads();
  #pragma unroll 4
  for (int i = 0; i < 64; ++i) acc += s_h[w][i] * cr[i * 64 + o];
  s_m[w][o] = lrelu(acc);
  __syncthreads();
  float gi0 = bih[o],       gh0 = bhh[o];
  float gi1 = bih[64 + o],  gh1 = bhh[64 + o];
  float gi2 = bih[128 + o], gh2 = bhh[128 + o];
  #pragma unroll 4
  for (int i = 0; i < 64; ++i) {
    float mv = s_m[w][i], hv = s_h[w][i];
    int io = i * 64 + o;
    gi0 += mv * wihT[io];
    gh0 += hv * whhT[io];
    gi1 += mv * wihT[4096 + io];
    gh1 += hv * whhT[4096 + io];
    gi2 += mv * wihT[8192 + io];
    gh2 += hv * whhT[8192 + io];
  }
  float r_ = sigm(gi0 + gh0);
  float z_ = sigm(gi1 + gh1);
  float cand = tanhf(gi2 + r_ * gh2);
  out_next[(size_t)nd * 64 + o] = (1.f - z_) * cand + z_ * hval;
}

// Set2Set + final linear: one block per graph (50 contiguous nodes).
__global__ __launch_bounds__(256) void k_s2s(const float* __restrict__ out,
    const float* __restrict__ wih, const float* __restrict__ whh,
    const float* __restrict__ bih, const float* __restrict__ bhh,
    const float* __restrict__ l1w, const float* __restrict__ l1b,
    float* __restrict__ dout) {
  __shared__ float s_out[NPG * 64];
  __shared__ float s_q[128];
  __shared__ float s_hs[64];
  __shared__ float s_cs[64];
  __shared__ float s_g[256];
  __shared__ float s_e[64];
  __shared__ float s_a[64];
  const int gb = blockIdx.x, tid = threadIdx.x;
  for (int t = tid; t < NPG * 64; t += 256)
    s_out[t] = out[(size_t)gb * NPG * 64 + t];
  if (tid < 128) s_q[tid] = 0.f;
  if (tid < 64) { s_hs[tid] = 0.f; s_cs[tid] = 0.f; }
  __syncthreads();
  for (int it = 0; it < S2S_STEPS; ++it) {
    float acc = bih[tid] + bhh[tid];
    const float* wi = wih + tid * 128;
    #pragma unroll 8
    for (int j = 0; j < 128; ++j) acc += s_q[j] * wi[j];
    const float* wh = whh + tid * 64;
    #pragma unroll 8
    for (int j = 0; j < 64; ++j) acc += s_hs[j] * wh[j];
    s_g[tid] = acc;
    __syncthreads();
    if (tid < 64) {
      float i_ = s_g[tid], f_ = s_g[64 + tid], g_ = s_g[128 + tid], o_ = s_g[192 + tid];
      float cs = sigm(f_) * s_cs[tid] + sigm(i_) * tanhf(g_);
      s_cs[tid] = cs;
      s_hs[tid] = sigm(o_) * tanhf(cs);
    }
    __syncthreads();
    {
      int wvi = tid >> 6, ln = tid & 63;
      for (int node = wvi; node < NPG; node += 4) {
        float p = s_out[node * 64 + ln] * s_hs[ln];
        #pragma unroll
        for (int m = 32; m; m >>= 1) p += __shfl_xor(p, m, 64);
        if (ln == 0) s_e[node] = p;
      }
    }
    __syncthreads();
    if (tid < 64) {
      float e = (tid < NPG) ? s_e[tid] : -1e30f;
      float mx = e;
      #pragma unroll
      for (int m = 32; m; m >>= 1) mx = fmaxf(mx, __shfl_xor(mx, m, 64));
      float a = (tid < NPG) ? expf(e - mx) : 0.f;
      float su = a;
      #pragma unroll
      for (int m = 32; m; m >>= 1) su += __shfl_xor(su, m, 64);
      s_a[tid] = a / su;
    }
    __syncthreads();
    if (tid < 64) {
      float r = 0.f;
      for (int n2 = 0; n2 < NPG; ++n2) r += s_a[n2] * s_out[n2 * 64 + tid];
      s_q[64 + tid] = r;
      s_q[tid] = s_hs[tid];
    }
    __syncthreads();
  }
  if (tid < 128) s_g[tid] = s_q[tid] * l1w[tid];
  __syncthreads();
  if (tid == 0) {
    float sm = 0.f;
    for (int j = 0; j < 128; ++j) sm += s_g[j];
    dout[gb] = sm + l1b[0];
  }
}

extern "C" void kernel_launch(void* const* d_in, const int* in_sizes, int n_in,
                              void* d_out, int out_size, void* d_ws, size_t ws_size,
                              hipStream_t stream) {
  (void)in_sizes; (void)n_in; (void)out_size; (void)ws_size;
  const float* x         = (const float*)d_in[0];
  const float* edge_attr = (const float*)d_in[1];
  const float* lin0_w    = (const float*)d_in[2];
  const float* lin0_b    = (const float*)d_in[3];
  const float* enet_w1   = (const float*)d_in[4];
  const float* enet_b1   = (const float*)d_in[5];
  const float* enet_w2   = (const float*)d_in[6];
  const float* enet_b2   = (const float*)d_in[7];
  const float* conv_root = (const float*)d_in[8];
  const float* conv_bias = (const float*)d_in[9];
  const float* gru_w_ih  = (const float*)d_in[10];
  const float* gru_w_hh  = (const float*)d_in[11];
  const float* gru_b_ih  = (const float*)d_in[12];
  const float* gru_b_hh  = (const float*)d_in[13];
  const float* s2s_w_ih  = (const float*)d_in[14];
  const float* s2s_w_hh  = (const float*)d_in[15];
  const float* s2s_b_ih  = (const float*)d_in[16];
  const float* s2s_b_hh  = (const float*)d_in[17];
  const float* lin1_w    = (const float*)d_in[18];
  const float* lin1_b    = (const float*)d_in[19];
  const int* edge_index  = (const int*)d_in[20];
  const int* srcp = edge_index;
  const int* dstp = edge_index + N_EDGES;

  char* ws = (char*)d_ws;
  size_t off = 0;
  auto carve = [&](size_t bytes) -> void* {
    void* p = ws + off;
    off += (bytes + 255) & ~(size_t)255;
    return p;
  };
  u16*   We    = (u16*)carve((size_t)N_EDGES * 4096 * 2);   // 163.84 MB
  u16*   h1    = (u16*)carve((size_t)N_EDGES * 128 * 2);    // 5.12 MB
  u16*   Bt    = (u16*)carve((size_t)4096 * 128 * 2);       // 1 MB
  float* b2p   = (float*)carve(4096 * 4);
  float* wihT  = (float*)carve(3 * 64 * 64 * 4);
  float* whhT  = (float*)carve(3 * 64 * 64 * 4);
  float* out_a = (float*)carve((size_t)N_NODES * 64 * 4);
  float* out_b = (float*)carve((size_t)N_NODES * 64 * 4);
  float* aggb  = (float*)carve((size_t)N_NODES * 64 * 4);
  float* cnt   = (float*)carve(N_NODES * 4);

  k_lin0<<<(N_NODES * DIM + 255) / 256, 256, 0, stream>>>(x, lin0_w, lin0_b, out_a);
  k_h1<<<(N_EDGES * 128 + 255) / 256, 256, 0, stream>>>(edge_attr, enet_w1, enet_b1, h1);
  k_prep<<<(4096 * 128 + 255) / 256, 256, 0, stream>>>(enet_w2, enet_b2,
      gru_w_ih, gru_w_hh, Bt, b2p, wihT, whhT);
  hipMemsetAsync(cnt, 0, N_NODES * 4, stream);
  k_cnt<<<(N_EDGES + 255) / 256, 256, 0, stream>>>(dstp, cnt);
  dim3 gg((N_EDGES + 127) / 128, 4096 / 128);
  k_gemm<<<gg, 256, 0, stream>>>(h1, Bt, b2p, We);

  float* cur = out_a;
  float* nxt = out_b;
  for (int s = 0; s < STEPS; ++s) {
    hipMemsetAsync(aggb, 0, (size_t)N_NODES * 64 * 4, stream);
    k_msg<<<N_EDGES / 4, 256, 0, stream>>>(We, cur, srcp, dstp, aggb);
    k_node<<<N_NODES / 4, 256, 0, stream>>>(aggb, cnt, cur, conv_root, conv_bias,
        wihT, whhT, gru_b_ih, gru_b_hh, nxt);
    float* t = cur; cur = nxt; nxt = t;
  }
  k_s2s<<<NB, 256, 0, stream>>>(cur, s2s_w_ih, s2s_w_hh, s2s_b_ih, s2s_b_hh,
      lin1_w, lin1_b, (float*)d_out);
}

// Round 4
// 388.257 us; speedup vs baseline: 8.2866x; 1.0016x over previous
//
#include <hip/hip_runtime.h>

#define N_NODES 10000
#define N_EDGES 20000
#define DIM 64
#define NF 14
#define NB 200
#define NPG 50      // nodes per graph (batch = repeat(arange(200), 50))
#define STEPS 4
#define S2S_STEPS 3

typedef short short8 __attribute__((ext_vector_type(8)));
typedef float f32x4 __attribute__((ext_vector_type(4)));
typedef unsigned short u16;

__device__ __forceinline__ u16 f2bf(float f) {
  unsigned u = __float_as_uint(f);
  u += 0x7FFFu + ((u >> 16) & 1u);   // RNE
  return (u16)(u >> 16);
}
__device__ __forceinline__ float bf2f(u16 h) {
  return __uint_as_float(((unsigned)h) << 16);
}
__device__ __forceinline__ float lrelu(float v) { return v > 0.f ? v : 0.01f * v; }
__device__ __forceinline__ float sigm(float x) { return 1.f / (1.f + expf(-x)); }

// Fused preprocessing: block-range split over 4 independent jobs.
//  [0,2500):      out0 = leaky_relu(x @ lin0_w + lin0_b)              [N,64]
//  [2500,12500):  h1 = bf16(leaky_relu(edge_attr @ enet_w1 + b1))     [E,128]
//  [12500,14548): Bt (perm-transposed W2 cols), b2p, wihT, whhT
//  [14548,14627): cnt = scatter-count of dst
// Column permutation for We streaming: stored col c = i8*512 + o*8 + k
// maps to weight element (i = i8*8+k, o), so k_msg's wave (lane=o) reads
// 1KB fully-contiguous chunks per i8.
__global__ __launch_bounds__(256) void k_prep_all(
    const float* __restrict__ x, const float* __restrict__ lin0_w,
    const float* __restrict__ lin0_b, float* __restrict__ out0,
    const float* __restrict__ ea, const float* __restrict__ w1,
    const float* __restrict__ b1, u16* __restrict__ h1,
    const float* __restrict__ w2, const float* __restrict__ b2,
    const float* __restrict__ wih, const float* __restrict__ whh,
    u16* __restrict__ Bt, float* __restrict__ b2p,
    float* __restrict__ wihT, float* __restrict__ whhT,
    const int* __restrict__ dst, float* __restrict__ cnt) {
  const int b = blockIdx.x, tid = threadIdx.x;
  if (b < 2500) {                      // lin0: 2500*256 = 640000 = N*64 exact
    int t = b * 256 + tid;
    int n = t >> 6, o = t & 63;
    float acc = lin0_b[o];
    #pragma unroll
    for (int f = 0; f < NF; ++f) acc += x[n * NF + f] * lin0_w[f * DIM + o];
    out0[t] = lrelu(acc);
  } else if (b < 12500) {              // h1: 10000*256 = E*128 exact
    int t = (b - 2500) * 256 + tid;
    int e = t >> 7, k = t & 127;
    float acc = b1[k];
    #pragma unroll
    for (int f = 0; f < 4; ++f) acc += ea[e * 4 + f] * w1[f * 128 + k];
    h1[t] = f2bf(lrelu(acc));
  } else if (b < 14548) {              // prep: 2048*256 = 4096*128 exact
    int t = (b - 12500) * 256 + tid;
    {
      int c = t >> 7, k = t & 127;
      int iw = (c >> 9) * 8 + (c & 7);
      int ow = (c >> 3) & 63;
      Bt[t] = f2bf(w2[(size_t)k * 4096 + iw * 64 + ow]);
    }
    if (t < 4096) {
      int iw = (t >> 9) * 8 + (t & 7);
      int ow = (t >> 3) & 63;
      b2p[t] = b2[iw * 64 + ow];
    }
    if (t < 3 * 64 * 64) {
      int p = t >> 12, rem = t & 4095, i = rem >> 6, o = rem & 63;
      int g = p * 64 + o;
      wihT[t] = wih[g * 64 + i];
      whhT[t] = whh[g * 64 + i];
    }
  } else {                             // cnt
    int t = (b - 14548) * 256 + tid;
    if (t < N_EDGES) atomicAdd(cnt + dst[t], 1.f);
  }
}

// We = h1 @ Bt^T + b2p   M=20000 N=4096 K=128, bf16 in/out, f32 accum.
// 128x128 tile, 4 waves. XOR-swizzled A/B LDS (16B granule g^(row&7));
// C repacked via LDS (stride 136 u16, conflict-free) -> 16B nt stores.
__global__ __launch_bounds__(256) void k_gemm(const u16* __restrict__ A,
    const u16* __restrict__ Bt, const float* __restrict__ bias,
    u16* __restrict__ C) {
  __shared__ __align__(16) u16 smem[2 * 128 * 128];   // 64 KB
  u16* As = smem;
  u16* Bs = smem + 128 * 128;
  const int tid = threadIdx.x;
  const int m0 = blockIdx.x * 128;   // m fastest: XCD owns a fixed m-stripe
  const int n0 = blockIdx.y * 128;
  #pragma unroll
  for (int it = 0; it < 8; ++it) {
    int chunk = tid + it * 256;          // 0..2047
    int row = chunk >> 4;                // 0..127
    int g = chunk & 15;                  // 16B granule index
    int gs = (g ^ (row & 7)) * 8;        // swizzled u16 offset
    int grow = m0 + row;
    short8 va = {0, 0, 0, 0, 0, 0, 0, 0};
    if (grow < N_EDGES) va = *(const short8*)(A + (size_t)grow * 128 + g * 8);
    *(short8*)(As + row * 128 + gs) = va;
    short8 vb = *(const short8*)(Bt + (size_t)(n0 + row) * 128 + g * 8);
    *(short8*)(Bs + row * 128 + gs) = vb;
  }
  __syncthreads();
  const int lane = tid & 63;
  const int wv = tid >> 6;     // wave -> column block wv*32
  const int lo = lane & 15;
  const int hi = lane >> 4;
  f32x4 acc[8][2];
  #pragma unroll
  for (int mf = 0; mf < 8; ++mf) {
    acc[mf][0] = (f32x4){0.f, 0.f, 0.f, 0.f};
    acc[mf][1] = (f32x4){0.f, 0.f, 0.f, 0.f};
  }
  #pragma unroll
  for (int kk = 0; kk < 4; ++kk) {
    // row&7 == lo&7 for every accessed row (row = q*16+lo or wv*32(+16)+lo)
    const int gsr = ((kk * 4 + hi) ^ (lo & 7)) * 8;
    short8 b0 = *(const short8*)(Bs + (wv * 32 + lo) * 128 + gsr);
    short8 b1 = *(const short8*)(Bs + (wv * 32 + 16 + lo) * 128 + gsr);
    #pragma unroll
    for (int mf = 0; mf < 8; ++mf) {
      short8 a = *(const short8*)(As + (mf * 16 + lo) * 128 + gsr);
      acc[mf][0] = __builtin_amdgcn_mfma_f32_16x16x32_bf16(a, b0, acc[mf][0], 0, 0, 0);
      acc[mf][1] = __builtin_amdgcn_mfma_f32_16x16x32_bf16(a, b1, acc[mf][1], 0, 0, 0);
    }
  }
  __syncthreads();   // done reading As/Bs; reuse as C-tile
  u16* Cs = smem;    // 128*136 u16 = 34816 B, fits in 64 KB smem
  #pragma unroll
  for (int nf = 0; nf < 2; ++nf) {
    int col = wv * 32 + nf * 16 + lo;    // C/D: col = lane&15
    float bv = bias[n0 + col];
    #pragma unroll
    for (int mf = 0; mf < 8; ++mf) {
      #pragma unroll
      for (int r = 0; r < 4; ++r) {
        int row = mf * 16 + hi * 4 + r;  // C/D: row = 4*(lane>>4)+reg
        Cs[row * 136 + col] = f2bf(acc[mf][nf][r] + bv);
      }
    }
  }
  __syncthreads();
  #pragma unroll
  for (int it = 0; it < 8; ++it) {
    int chunk = tid + it * 256;
    int row = chunk >> 4;
    int c8 = (chunk & 15) * 8;
    int grow = m0 + row;
    if (grow < N_EDGES) {
      short8 v = *(const short8*)(Cs + row * 136 + c8);
      // nt: C (We) has no L2 reuse here; keep A/B-stripe resident instead
      __builtin_nontemporal_store(v, (short8*)(C + (size_t)grow * 4096 + n0 + c8));
    }
  }
}

// msg[e,o] = sum_i out[src[e],i] * We_perm; perfectly coalesced We stream.
// Wave = edge, lane = o. Chunk i8: lane o loads 16B at e*8KB + i8*1KB + o*16B
// (wave covers 1KB contiguous), pairs with broadcast out[src][i8*8+k].
__global__ __launch_bounds__(256) void k_msg(const u16* __restrict__ We,
    const float* __restrict__ out, const int* __restrict__ src,
    const int* __restrict__ dst, float* __restrict__ agg) {
  __shared__ float s_o[4][64];
  const int w = threadIdx.x >> 6, o = threadIdx.x & 63;
  const int e = blockIdx.x * 4 + w;          // grid exact: 5000*4 = 20000
  const int s = __builtin_amdgcn_readfirstlane(src[e]);
  const int d = __builtin_amdgcn_readfirstlane(dst[e]);
  s_o[w][o] = out[(size_t)s * 64 + o];
  __syncthreads();
  const u16* wp = We + (size_t)e * 4096 + o * 8;
  float acc = 0.f;
  #pragma unroll
  for (int i8 = 0; i8 < 8; ++i8) {
    short8 wv = *(const short8*)(wp + i8 * 512);
    f32x4 o0 = *(const f32x4*)(&s_o[w][i8 * 8]);
    f32x4 o1 = *(const f32x4*)(&s_o[w][i8 * 8 + 4]);
    acc += bf2f((u16)wv[0]) * o0[0] + bf2f((u16)wv[1]) * o0[1]
         + bf2f((u16)wv[2]) * o0[2] + bf2f((u16)wv[3]) * o0[3]
         + bf2f((u16)wv[4]) * o1[0] + bf2f((u16)wv[5]) * o1[1]
         + bf2f((u16)wv[6]) * o1[2] + bf2f((u16)wv[7]) * o1[3];
  }
  atomicAdd(agg + (size_t)d * 64 + o, acc);
}

// Node update: one node per wave, lane = output dim. No register arrays.
// m = lrelu(agg/denom + out@conv_root + cbias); GRU(h=out) -> out_next.
// Also re-zeroes agg for the next step's atomics (saves per-step memset).
__global__ __launch_bounds__(256) void k_node(float* __restrict__ agg,
    const float* __restrict__ cnt, const float* __restrict__ out_cur,
    const float* __restrict__ cr,        // conv_root [i][o], o contiguous
    const float* __restrict__ cbias,
    const float* __restrict__ wihT, const float* __restrict__ whhT,
    const float* __restrict__ bih, const float* __restrict__ bhh,
    float* __restrict__ out_next) {
  __shared__ float s_h[4][64];
  __shared__ float s_m[4][64];
  const int w = threadIdx.x >> 6, o = threadIdx.x & 63;
  const int nd = blockIdx.x * 4 + w;          // 2500 blocks * 4 = 10000 exact
  const float hval = out_cur[(size_t)nd * 64 + o];
  s_h[w][o] = hval;
  float acc = agg[(size_t)nd * 64 + o] / fmaxf(cnt[nd], 1.f) + cbias[o];
  agg[(size_t)nd * 64 + o] = 0.f;             // reset for next k_msg
  __syncthreads();
  #pragma unroll 4
  for (int i = 0; i < 64; ++i) acc += s_h[w][i] * cr[i * 64 + o];
  s_m[w][o] = lrelu(acc);
  __syncthreads();
  float gi0 = bih[o],       gh0 = bhh[o];
  float gi1 = bih[64 + o],  gh1 = bhh[64 + o];
  float gi2 = bih[128 + o], gh2 = bhh[128 + o];
  #pragma unroll 4
  for (int i = 0; i < 64; ++i) {
    float mv = s_m[w][i], hv = s_h[w][i];
    int io = i * 64 + o;
    gi0 += mv * wihT[io];
    gh0 += hv * whhT[io];
    gi1 += mv * wihT[4096 + io];
    gh1 += hv * whhT[4096 + io];
    gi2 += mv * wihT[8192 + io];
    gh2 += hv * whhT[8192 + io];
  }
  float r_ = sigm(gi0 + gh0);
  float z_ = sigm(gi1 + gh1);
  float cand = tanhf(gi2 + r_ * gh2);
  out_next[(size_t)nd * 64 + o] = (1.f - z_) * cand + z_ * hval;
}

// Set2Set + final linear: one block per graph (50 contiguous nodes).
__global__ __launch_bounds__(256) void k_s2s(const float* __restrict__ out,
    const float* __restrict__ wih, const float* __restrict__ whh,
    const float* __restrict__ bih, const float* __restrict__ bhh,
    const float* __restrict__ l1w, const float* __restrict__ l1b,
    float* __restrict__ dout) {
  __shared__ float s_out[NPG * 64];
  __shared__ float s_q[128];
  __shared__ float s_hs[64];
  __shared__ float s_cs[64];
  __shared__ float s_g[256];
  __shared__ float s_e[64];
  __shared__ float s_a[64];
  const int gb = blockIdx.x, tid = threadIdx.x;
  for (int t = tid; t < NPG * 64; t += 256)
    s_out[t] = out[(size_t)gb * NPG * 64 + t];
  if (tid < 128) s_q[tid] = 0.f;
  if (tid < 64) { s_hs[tid] = 0.f; s_cs[tid] = 0.f; }
  __syncthreads();
  for (int it = 0; it < S2S_STEPS; ++it) {
    float acc = bih[tid] + bhh[tid];
    const float* wi = wih + tid * 128;
    #pragma unroll 8
    for (int j = 0; j < 128; ++j) acc += s_q[j] * wi[j];
    const float* wh = whh + tid * 64;
    #pragma unroll 8
    for (int j = 0; j < 64; ++j) acc += s_hs[j] * wh[j];
    s_g[tid] = acc;
    __syncthreads();
    if (tid < 64) {
      float i_ = s_g[tid], f_ = s_g[64 + tid], g_ = s_g[128 + tid], o_ = s_g[192 + tid];
      float cs = sigm(f_) * s_cs[tid] + sigm(i_) * tanhf(g_);
      s_cs[tid] = cs;
      s_hs[tid] = sigm(o_) * tanhf(cs);
    }
    __syncthreads();
    {
      int wvi = tid >> 6, ln = tid & 63;
      for (int node = wvi; node < NPG; node += 4) {
        float p = s_out[node * 64 + ln] * s_hs[ln];
        #pragma unroll
        for (int m = 32; m; m >>= 1) p += __shfl_xor(p, m, 64);
        if (ln == 0) s_e[node] = p;
      }
    }
    __syncthreads();
    if (tid < 64) {
      float e = (tid < NPG) ? s_e[tid] : -1e30f;
      float mx = e;
      #pragma unroll
      for (int m = 32; m; m >>= 1) mx = fmaxf(mx, __shfl_xor(mx, m, 64));
      float a = (tid < NPG) ? expf(e - mx) : 0.f;
      float su = a;
      #pragma unroll
      for (int m = 32; m; m >>= 1) su += __shfl_xor(su, m, 64);
      s_a[tid] = a / su;
    }
    __syncthreads();
    if (tid < 64) {
      float r = 0.f;
      for (int n2 = 0; n2 < NPG; ++n2) r += s_a[n2] * s_out[n2 * 64 + tid];
      s_q[64 + tid] = r;
      s_q[tid] = s_hs[tid];
    }
    __syncthreads();
  }
  if (tid < 128) s_g[tid] = s_q[tid] * l1w[tid];
  __syncthreads();
  if (tid == 0) {
    float sm = 0.f;
    for (int j = 0; j < 128; ++j) sm += s_g[j];
    dout[gb] = sm + l1b[0];
  }
}

extern "C" void kernel_launch(void* const* d_in, const int* in_sizes, int n_in,
                              void* d_out, int out_size, void* d_ws, size_t ws_size,
                              hipStream_t stream) {
  (void)in_sizes; (void)n_in; (void)out_size; (void)ws_size;
  const float* x         = (const float*)d_in[0];
  const float* edge_attr = (const float*)d_in[1];
  const float* lin0_w    = (const float*)d_in[2];
  const float* lin0_b    = (const float*)d_in[3];
  const float* enet_w1   = (const float*)d_in[4];
  const float* enet_b1   = (const float*)d_in[5];
  const float* enet_w2   = (const float*)d_in[6];
  const float* enet_b2   = (const float*)d_in[7];
  const float* conv_root = (const float*)d_in[8];
  const float* conv_bias = (const float*)d_in[9];
  const float* gru_w_ih  = (const float*)d_in[10];
  const float* gru_w_hh  = (const float*)d_in[11];
  const float* gru_b_ih  = (const float*)d_in[12];
  const float* gru_b_hh  = (const float*)d_in[13];
  const float* s2s_w_ih  = (const float*)d_in[14];
  const float* s2s_w_hh  = (const float*)d_in[15];
  const float* s2s_b_ih  = (const float*)d_in[16];
  const float* s2s_b_hh  = (const float*)d_in[17];
  const float* lin1_w    = (const float*)d_in[18];
  const float* lin1_b    = (const float*)d_in[19];
  const int* edge_index  = (const int*)d_in[20];
  const int* srcp = edge_index;
  const int* dstp = edge_index + N_EDGES;

  char* ws = (char*)d_ws;
  size_t off = 0;
  auto carve = [&](size_t bytes) -> void* {
    void* p = ws + off;
    off += (bytes + 255) & ~(size_t)255;
    return p;
  };
  u16*   We    = (u16*)carve((size_t)N_EDGES * 4096 * 2);   // 163.84 MB
  u16*   h1    = (u16*)carve((size_t)N_EDGES * 128 * 2);    // 5.12 MB
  u16*   Bt    = (u16*)carve((size_t)4096 * 128 * 2);       // 1 MB
  float* b2p   = (float*)carve(4096 * 4);
  float* wihT  = (float*)carve(3 * 64 * 64 * 4);
  float* whhT  = (float*)carve(3 * 64 * 64 * 4);
  float* out_a = (float*)carve((size_t)N_NODES * 64 * 4);
  float* out_b = (float*)carve((size_t)N_NODES * 64 * 4);
  float* aggb  = (float*)carve((size_t)N_NODES * 64 * 4);
  float* cnt   = (float*)carve(N_NODES * 4);

  hipMemsetAsync(cnt, 0, N_NODES * 4, stream);
  hipMemsetAsync(aggb, 0, (size_t)N_NODES * 64 * 4, stream);
  k_prep_all<<<14627, 256, 0, stream>>>(
      x, lin0_w, lin0_b, out_a,
      edge_attr, enet_w1, enet_b1, h1,
      enet_w2, enet_b2, gru_w_ih, gru_w_hh, Bt, b2p, wihT, whhT,
      dstp, cnt);
  dim3 gg((N_EDGES + 127) / 128, 4096 / 128);
  k_gemm<<<gg, 256, 0, stream>>>(h1, Bt, b2p, We);

  float* cur = out_a;
  float* nxt = out_b;
  for (int s = 0; s < STEPS; ++s) {
    k_msg<<<N_EDGES / 4, 256, 0, stream>>>(We, cur, srcp, dstp, aggb);
    k_node<<<N_NODES / 4, 256, 0, stream>>>(aggb, cnt, cur, conv_root, conv_bias,
        wihT, whhT, gru_b_ih, gru_b_hh, nxt);
    float* t = cur; cur = nxt; nxt = t;
  }
  k_s2s<<<NB, 256, 0, stream>>>(cur, s2s_w_ih, s2s_w_hh, s2s_b_ih, s2s_b_hh,
      lin1_w, lin1_b, (float*)d_out);
}